// Round 1
// baseline (840.742 us; speedup 1.0000x reference)
//
#include <hip/hip_runtime.h>
#include <math.h>

// Problem constants (fixed by setup_inputs: B=4, L=2048)
#define BB      4
#define LL      2048
#define KNB     30
#define NRES    (BB*LL)          // 8192
#define NEDGE   (NRES*KNB)       // 245760
#define EDGE_IN 416              // 16 pos + 25*16 RBF
#define MT      32               // edges per block in edge kernel

__device__ __constant__ int d_PA[25] = {0,1,2,3,4,0,0,0,0,1,1,1,4,4,3,1,2,3,4,2,3,4,2,3,2};
__device__ __constant__ int d_PB[25] = {0,1,2,3,4,1,2,3,4,2,3,4,2,3,2,0,0,0,0,1,1,1,4,4,3};

// ---------------------------------------------------------------------------
// Kernel 1: per-residue atom construction.  atoms[r][5][3] = [Ca,N,C,O,Cb]
// ---------------------------------------------------------------------------
__global__ __launch_bounds__(256) void atoms_kernel(const float* __restrict__ X,
                                                    float* __restrict__ atoms) {
    int r = blockIdx.x * blockDim.x + threadIdx.x;
    if (r >= NRES) return;
    const float* xr = X + (size_t)r * 12;
    float Nx = xr[0],  Ny = xr[1],  Nz = xr[2];
    float Ax = xr[3],  Ay = xr[4],  Az = xr[5];   // Ca
    float Cx = xr[6],  Cy = xr[7],  Cz = xr[8];
    float Ox = xr[9],  Oy = xr[10], Oz = xr[11];
    float bx = Ax - Nx, by = Ay - Ny, bz = Az - Nz;
    float cx = Cx - Ax, cy = Cy - Ay, cz = Cz - Az;
    float ax = by * cz - bz * cy;
    float ay = bz * cx - bx * cz;
    float az = bx * cy - by * cx;
    float Cbx = -0.58273431f * ax + 0.56802827f * bx - 0.54067466f * cx + Ax;
    float Cby = -0.58273431f * ay + 0.56802827f * by - 0.54067466f * cy + Ay;
    float Cbz = -0.58273431f * az + 0.56802827f * bz - 0.54067466f * cz + Az;
    float* o = atoms + (size_t)r * 15;
    o[0]  = Ax;  o[1]  = Ay;  o[2]  = Az;    // Ca (stack idx 0)
    o[3]  = Nx;  o[4]  = Ny;  o[5]  = Nz;    // N  (1)
    o[6]  = Cx;  o[7]  = Cy;  o[8]  = Cz;    // C  (2)
    o[9]  = Ox;  o[10] = Oy;  o[11] = Oz;    // O  (3)
    o[12] = Cbx; o[13] = Cby; o[14] = Cbz;   // Cb (4)
}

// ---------------------------------------------------------------------------
// Kernel 2: top-K neighbor selection.  One block per residue (b,i).
// Matches jax.lax.top_k(-D_adjust) semantics: K smallest D_adjust, ties by
// lower index.  Distances computed with fp-contract OFF so they are
// bit-identical to the numpy fp32 reference (no boundary-flip risk).
// ---------------------------------------------------------------------------
__global__ __launch_bounds__(256) void topk_kernel(const float* __restrict__ X,
                                                   const float* __restrict__ mask,
                                                   int* __restrict__ E_idx) {
#pragma clang fp contract(off)
    __shared__ float Dv[LL];
    __shared__ float wred[4];
    __shared__ int   wredi[4];
    __shared__ float s_max;

    int bi = blockIdx.x;            // b*L + i
    int b  = bi / LL;
    int t  = threadIdx.x;

    const float* cai = X + ((size_t)bi * 4 + 1) * 3;
    float cx = cai[0], cy = cai[1], cz = cai[2];
    float mi = mask[bi];

    float lmax = 0.0f;
    for (int j = t; j < LL; j += 256) {
        const float* cj = X + (((size_t)(b * LL + j)) * 4 + 1) * 3;
        float dx = cx - cj[0], dy = cy - cj[1], dz = cz - cj[2];
        float ssq = ((dx * dx + dy * dy) + dz * dz) + 1e-6f;
        float m2  = mask[b * LL + j] * mi;
        float Dj  = m2 * sqrtf(ssq);
        Dv[j] = Dj;
        lmax = fmaxf(lmax, Dj);
    }
    // block-reduce row max (needed for mask adjustment; exact no-op when mask==1)
    for (int off = 32; off; off >>= 1) lmax = fmaxf(lmax, __shfl_down(lmax, off));
    if ((t & 63) == 0) wred[t >> 6] = lmax;
    __syncthreads();
    if (t == 0) {
        float m = wred[0];
        for (int w = 1; w < 4; w++) m = fmaxf(m, wred[w]);
        s_max = m;
    }
    __syncthreads();
    float dmax = s_max;
    for (int j = t; j < LL; j += 256) {
        float m2 = mask[b * LL + j] * mi;
        Dv[j] = Dv[j] + (1.0f - m2) * dmax;
    }
    __syncthreads();

    // iterative extract-min with (value, index) tie-break
    for (int k = 0; k < KNB; k++) {
        float bv = 3.4e38f;
        int   bj = LL;
        for (int j = t; j < LL; j += 256) {
            float v = Dv[j];
            if (v < bv) { bv = v; bj = j; }   // ascending j per thread -> lowest idx kept
        }
        for (int off = 32; off; off >>= 1) {
            float ov = __shfl_down(bv, off);
            int   oj = __shfl_down(bj, off);
            if (ov < bv || (ov == bv && oj < bj)) { bv = ov; bj = oj; }
        }
        if ((t & 63) == 0) { wred[t >> 6] = bv; wredi[t >> 6] = bj; }
        __syncthreads();
        if (t == 0) {
            for (int w = 1; w < 4; w++) {
                if (wred[w] < bv || (wred[w] == bv && wredi[w] < bj)) { bv = wred[w]; bj = wredi[w]; }
            }
            E_idx[(size_t)bi * KNB + k] = bj;
            Dv[bj] = 3.4e38f;
        }
        __syncthreads();
    }
}

// ---------------------------------------------------------------------------
// Kernel 3: edge featurization + 416x128 matmul + LayerNorm.
// One block = MT(32) edges.  A-tile stored transposed [416][32] in LDS so the
// GEMM A-read is one ds_read_b128 per K-step (wave-broadcast, conflict-free).
// Register tile: 4 edges x 4 features per thread.  LN via __shfl_xor, no LDS.
// ---------------------------------------------------------------------------
__global__ __launch_bounds__(256) void edge_kernel(const float* __restrict__ atoms,
                                                   const int* __restrict__ E_idx,
                                                   const int* __restrict__ resi,
                                                   const float* __restrict__ W_pos,
                                                   const float* __restrict__ b_pos,
                                                   const float* __restrict__ W_edge,
                                                   const float* __restrict__ gamma,
                                                   const float* __restrict__ beta,
                                                   float* __restrict__ out) {
    __shared__ float As[EDGE_IN * MT];   // transposed A-tile [c][e], 52 KB
    __shared__ float Ai[MT][16];         // i-side atoms (15 used)
    __shared__ float Bj[MT][16];         // j-side atoms
    __shared__ float Dl[MT][26];         // 25 pair distances
    __shared__ int   s_d[MT];            // pos one-hot bucket
    __shared__ int   s_gi[MT], s_gj[MT];

    int t  = threadIdx.x;
    int e0 = blockIdx.x * MT;

    if (t < MT) {
        int e  = e0 + t;
        int gi = e / KNB;
        int k  = e - gi * KNB;
        int b  = gi / LL;
        int j  = E_idx[(size_t)gi * KNB + k];
        int gj = b * LL + j;
        s_gi[t] = gi;
        s_gj[t] = gj;
        int off = resi[gi] - resi[gj];
        int d = off + 32;
        d = d < 0 ? 0 : (d > 64 ? 64 : d);
        s_d[t] = d;
    }
    __syncthreads();

    for (int idx = t; idx < MT * 15; idx += 256) {
        int e = idx / 15, c = idx - e * 15;
        Ai[e][c] = atoms[(size_t)s_gi[e] * 15 + c];
        Bj[e][c] = atoms[(size_t)s_gj[e] * 15 + c];
    }
    __syncthreads();

    for (int idx = t; idx < MT * 25; idx += 256) {
        int e = idx / 25, p = idx - e * 25;
        int a = d_PA[p], bb = d_PB[p];
        float dx = Ai[e][a * 3 + 0] - Bj[e][bb * 3 + 0];
        float dy = Ai[e][a * 3 + 1] - Bj[e][bb * 3 + 1];
        float dz = Ai[e][a * 3 + 2] - Bj[e][bb * 3 + 2];
        Dl[e][p] = sqrtf(dx * dx + dy * dy + dz * dz + 1e-6f);
    }
    __syncthreads();

    // Fill transposed A-tile: thread owns edge e=t&31, strides over c.
    {
        int e = t & 31;
        int dpos = s_d[e];
        for (int c = (t >> 5); c < EDGE_IN; c += 8) {
            float v;
            if (c < 16) {
                v = W_pos[dpos * 16 + c] + b_pos[c];
            } else {
                int c2 = c - 16;
                int p = c2 >> 4, r = c2 & 15;
                float mu = 2.0f + (float)r * (20.0f / 15.0f);
                float z = (Dl[e][p] - mu) * 0.8f;     // sigma = 1.25
                v = expf(-(z * z));
            }
            As[c * MT + e] = v;
        }
    }
    __syncthreads();

    // GEMM: 32 edges x 416 x 128.  4x4 register tile per thread.
    int tx = t & 31;          // feature group: f0 = tx*4
    int ty = t >> 5;          // edge group:    eb = ty*4
    int f0 = tx * 4;
    int eb = ty * 4;
    float acc[4][4] = {{0.f,0.f,0.f,0.f},{0.f,0.f,0.f,0.f},{0.f,0.f,0.f,0.f},{0.f,0.f,0.f,0.f}};

#pragma unroll 4
    for (int kk = 0; kk < EDGE_IN; kk++) {
        float4 av = *(const float4*)&As[kk * MT + eb];
        float4 wv = *(const float4*)&W_edge[(size_t)kk * 128 + f0];
        acc[0][0] += av.x * wv.x; acc[0][1] += av.x * wv.y; acc[0][2] += av.x * wv.z; acc[0][3] += av.x * wv.w;
        acc[1][0] += av.y * wv.x; acc[1][1] += av.y * wv.y; acc[1][2] += av.y * wv.z; acc[1][3] += av.y * wv.w;
        acc[2][0] += av.z * wv.x; acc[2][1] += av.z * wv.y; acc[2][2] += av.z * wv.z; acc[2][3] += av.z * wv.w;
        acc[3][0] += av.w * wv.x; acc[3][1] += av.w * wv.y; acc[3][2] += av.w * wv.z; acc[3][3] += av.w * wv.w;
    }

    // LayerNorm over 128 features (32 tx-lanes x 4 feats), per edge.
    float4 gv = *(const float4*)&gamma[f0];
    float4 bv = *(const float4*)&beta[f0];
#pragma unroll
    for (int i = 0; i < 4; i++) {
        float s = acc[i][0] + acc[i][1] + acc[i][2] + acc[i][3];
        for (int m = 1; m <= 16; m <<= 1) s += __shfl_xor(s, m);
        float mu = s * (1.0f / 128.0f);
        float d0 = acc[i][0] - mu, d1 = acc[i][1] - mu, d2 = acc[i][2] - mu, d3 = acc[i][3] - mu;
        float v = d0 * d0 + d1 * d1 + d2 * d2 + d3 * d3;
        for (int m = 1; m <= 16; m <<= 1) v += __shfl_xor(v, m);
        float rstd = rsqrtf(v * (1.0f / 128.0f) + 1e-5f);
        float4 o;
        o.x = d0 * rstd * gv.x + bv.x;
        o.y = d1 * rstd * gv.y + bv.y;
        o.z = d2 * rstd * gv.z + bv.z;
        o.w = d3 * rstd * gv.w + bv.w;
        *(float4*)&out[(size_t)(e0 + eb + i) * 128 + f0] = o;
    }
}

// ---------------------------------------------------------------------------
extern "C" void kernel_launch(void* const* d_in, const int* in_sizes, int n_in,
                              void* d_out, int out_size, void* d_ws, size_t ws_size,
                              hipStream_t stream) {
    const float* X      = (const float*)d_in[0];
    const float* mask   = (const float*)d_in[1];
    const int*   resi   = (const int*)  d_in[2];
    const float* W_pos  = (const float*)d_in[3];
    const float* b_pos  = (const float*)d_in[4];
    const float* W_edge = (const float*)d_in[5];
    const float* gamma  = (const float*)d_in[6];
    const float* beta   = (const float*)d_in[7];
    float* out = (float*)d_out;

    float* atoms = (float*)d_ws;                                   // 8192*15*4 = 491520 B
    int*   E_idx = (int*)((char*)d_ws + (size_t)NRES * 15 * 4);    // 8192*30*4 = 983040 B

    atoms_kernel<<<(NRES + 255) / 256, 256, 0, stream>>>(X, atoms);
    topk_kernel<<<NRES, 256, 0, stream>>>(X, mask, E_idx);
    edge_kernel<<<NEDGE / MT, 256, 0, stream>>>(atoms, E_idx, resi,
                                                W_pos, b_pos, W_edge, gamma, beta, out);
}

// Round 4
// 419.364 us; speedup vs baseline: 2.0048x; 2.0048x over previous
//
#include <hip/hip_runtime.h>
#include <hip/hip_bf16.h>
#include <math.h>

// Problem constants (fixed by setup_inputs: B=4, L=2048)
#define BB      4
#define LL      2048
#define KNB     30
#define NRES    (BB*LL)          // 8192
#define NEDGE   (NRES*KNB)       // 245760
#define EDGE_IN 416              // 16 pos + 25*16 RBF = 13 * 32
#define KT      13               // K-tiles of 32
#define ME      32               // edges per block in edge kernel
#define ASTRIDE 424              // A-tile row stride in fp16 (848 B, 16B-aligned)

typedef __attribute__((ext_vector_type(8))) _Float16 half8;
typedef __attribute__((ext_vector_type(4))) float floatx4;

__device__ __constant__ int d_PA[25] = {0,1,2,3,4,0,0,0,0,1,1,1,4,4,3,1,2,3,4,2,3,4,2,3,2};
__device__ __constant__ int d_PB[25] = {0,1,2,3,4,1,2,3,4,2,3,4,2,3,2,0,0,0,0,1,1,1,4,4,3};

__device__ __forceinline__ unsigned short f2h_bits(float x) {
    _Float16 h = (_Float16)x;
    union { _Float16 h; unsigned short u; } v; v.h = h;
    return v.u;
}
__device__ __forceinline__ unsigned pack2h(float a, float b) {
    return (unsigned)f2h_bits(a) | ((unsigned)f2h_bits(b) << 16);
}

// ---------------------------------------------------------------------------
// Kernel 1: per-residue atom construction.  atoms[r][5][3] = [Ca,N,C,O,Cb]
// ---------------------------------------------------------------------------
__global__ __launch_bounds__(256) void atoms_kernel(const float* __restrict__ X,
                                                    float* __restrict__ atoms) {
    int r = blockIdx.x * blockDim.x + threadIdx.x;
    if (r >= NRES) return;
    const float* xr = X + (size_t)r * 12;
    float Nx = xr[0],  Ny = xr[1],  Nz = xr[2];
    float Ax = xr[3],  Ay = xr[4],  Az = xr[5];   // Ca
    float Cx = xr[6],  Cy = xr[7],  Cz = xr[8];
    float Ox = xr[9],  Oy = xr[10], Oz = xr[11];
    float bx = Ax - Nx, by = Ay - Ny, bz = Az - Nz;
    float cx = Cx - Ax, cy = Cy - Ay, cz = Cz - Az;
    float ax = by * cz - bz * cy;
    float ay = bz * cx - bx * cz;
    float az = bx * cy - by * cx;
    float Cbx = -0.58273431f * ax + 0.56802827f * bx - 0.54067466f * cx + Ax;
    float Cby = -0.58273431f * ay + 0.56802827f * by - 0.54067466f * cy + Ay;
    float Cbz = -0.58273431f * az + 0.56802827f * bz - 0.54067466f * cz + Az;
    float* o = atoms + (size_t)r * 15;
    o[0]  = Ax;  o[1]  = Ay;  o[2]  = Az;
    o[3]  = Nx;  o[4]  = Ny;  o[5]  = Nz;
    o[6]  = Cx;  o[7]  = Cy;  o[8]  = Cz;
    o[9]  = Ox;  o[10] = Oy;  o[11] = Oz;
    o[12] = Cbx; o[13] = Cby; o[14] = Cbz;
}

// ---------------------------------------------------------------------------
// Kernel 2: top-K neighbor selection — ONE WAVE PER RESIDUE.
// Distances bit-exact vs the fp32 numpy pipeline (contract off, same expr).
// 30 rounds of in-wave lexicographic (value, index) min via __shfl_xor —
// no __syncthreads at all.  LDS lane-major => conflict-free rescans.
// ---------------------------------------------------------------------------
__global__ __launch_bounds__(256) void topk_kernel(const float* __restrict__ X,
                                                   const float* __restrict__ mask,
                                                   int* __restrict__ E_idx) {
#pragma clang fp contract(off)
    __shared__ float Dv[4][LL];

    int t    = threadIdx.x;
    int wid  = t >> 6;
    int lane = t & 63;
    int bi   = blockIdx.x * 4 + wid;      // residue
    int b    = bi >> 11;

    const float* cai = X + ((size_t)bi * 4 + 1) * 3;
    float cx = cai[0], cy = cai[1], cz = cai[2];
    float mi = mask[bi];
    float* dv = Dv[wid];

    float lmax = 0.0f;
#pragma unroll 4
    for (int i = 0; i < 32; i++) {
        int j = i * 64 + lane;
        const float* cj = X + (((size_t)((b << 11) + j)) * 4 + 1) * 3;
        float dx = cx - cj[0], dy = cy - cj[1], dz = cz - cj[2];
        float ssq = ((dx * dx + dy * dy) + dz * dz) + 1e-6f;
        float m2  = mask[(b << 11) + j] * mi;
        float Dj  = m2 * sqrtf(ssq);
        dv[j] = Dj;
        lmax = fmaxf(lmax, Dj);
    }
    for (int off = 32; off; off >>= 1) lmax = fmaxf(lmax, __shfl_xor(lmax, off));
    // mask adjustment (exact no-op when mask==1)
#pragma unroll 4
    for (int i = 0; i < 32; i++) {
        int j = i * 64 + lane;
        float m2 = mask[(b << 11) + j] * mi;
        dv[j] = dv[j] + (1.0f - m2) * lmax;
    }

    for (int k = 0; k < KNB; k++) {
        float bv = 3.4e38f;
        int   bj = LL;
#pragma unroll 8
        for (int i = 0; i < 32; i++) {
            int j = i * 64 + lane;
            float v = dv[j];
            if (v < bv) { bv = v; bj = j; }     // ascending j -> lowest idx kept
        }
        for (int off = 1; off < 64; off <<= 1) {
            float ov = __shfl_xor(bv, off);
            int   oj = __shfl_xor(bj, off);
            if (ov < bv || (ov == bv && oj < bj)) { bv = ov; bj = oj; }
        }
        // all 64 lanes agree on (bv, bj)
        if (lane == 0) E_idx[(size_t)bi * KNB + k] = bj;
        if (lane == (bj & 63)) dv[bj] = 3.4e38f;   // single-writer invalidate
    }
}

// ---------------------------------------------------------------------------
// Kernel 2.5: pre-swizzle W_edge (fp32 [416][128]) into SPLIT fp16 B-fragment
// order: Wh = fp16(W), Wl = fp16(W - Wh).  Layout [kk][nt][lane] of half8:
// element holds W[k = kk*32 + (lane>>4)*8 + j][n = nt*16 + (lane&15)].
// ---------------------------------------------------------------------------
__global__ __launch_bounds__(256) void wprep_kernel(const float* __restrict__ W_edge,
                                                    half8* __restrict__ Wfh,
                                                    half8* __restrict__ Wfl) {
    int t = blockIdx.x * blockDim.x + threadIdx.x;
    if (t >= KT * 8 * 64) return;
    int kk   = t >> 9;
    int rem  = t & 511;
    int nt   = rem >> 6;
    int lane = rem & 63;
    int n  = nt * 16 + (lane & 15);
    int kb = kk * 32 + (lane >> 4) * 8;
    half8 vh, vl;
#pragma unroll
    for (int j = 0; j < 8; j++) {
        float w = W_edge[(size_t)(kb + j) * 128 + n];
        _Float16 wh = (_Float16)w;
        vh[j] = wh;
        vl[j] = (_Float16)(w - (float)wh);
    }
    Wfh[t] = vh;
    Wfl[t] = vl;
}

// ---------------------------------------------------------------------------
// Kernel 3: edge featurization (SPLIT fp16 A-tile) + 3-term MFMA GEMM + LN.
// Block = 32 edges.  Wave w: edge strip (w&1)*16, feature half (w>>1)*64.
// E = Ah*Wh + Al*Wh + Ah*Wl  (fp32 accum; dropped Al*Wl ~ 2^-22) — effective
// fp32 GEMM precision at MFMA speed.  LN combines the two feature halves via
// a small LDS partial buffer.
// ---------------------------------------------------------------------------
__global__ __launch_bounds__(256) void edge_kernel(const float* __restrict__ atoms,
                                                   const int* __restrict__ E_idx,
                                                   const int* __restrict__ resi,
                                                   const float* __restrict__ W_pos,
                                                   const float* __restrict__ b_pos,
                                                   const half8* __restrict__ Wfh,
                                                   const half8* __restrict__ Wfl,
                                                   const float* __restrict__ gamma,
                                                   const float* __restrict__ beta,
                                                   float* __restrict__ out) {
    __shared__ _Float16 Ah[ME * ASTRIDE];          // 27136 B
    __shared__ _Float16 Al[ME * ASTRIDE];          // 27136 B
    __shared__ float Dl[ME][26];                   //  3328 B
    __shared__ float redS[2][ME];                  //   256 B
    __shared__ int   s_gi[ME], s_gj[ME], s_d[ME];  //   384 B

    int t  = threadIdx.x;
    int e0 = blockIdx.x * ME;

    if (t < ME) {
        int e  = e0 + t;
        int gi = e / KNB;
        int k  = e - gi * KNB;
        int b  = gi >> 11;
        int j  = E_idx[(size_t)gi * KNB + k];
        s_gi[t] = gi;
        s_gj[t] = (b << 11) + j;
        int off = resi[gi] - resi[(b << 11) + j];
        int d = off + 32;
        s_d[t] = d < 0 ? 0 : (d > 64 ? 64 : d);
    }
    __syncthreads();

    for (int idx = t; idx < ME * 25; idx += 256) {
        int e = idx / 25, p = idx - e * 25;
        const float* Ar = atoms + (size_t)s_gi[e] * 15 + d_PA[p] * 3;
        const float* Br = atoms + (size_t)s_gj[e] * 15 + d_PB[p] * 3;
        float dx = Ar[0] - Br[0];
        float dy = Ar[1] - Br[1];
        float dz = Ar[2] - Br[2];
        Dl[e][p] = sqrtf(dx * dx + dy * dy + dz * dz + 1e-6f);
    }
    __syncthreads();

    // --- fill split fp16 A-tile: 8 threads per edge ---
    {
        int e  = t >> 3;           // 0..31
        int j8 = t & 7;
        const float* dle = Dl[e];
        _Float16* ah = &Ah[e * ASTRIDE];
        _Float16* al = &Al[e * ASTRIDE];
        if (j8 < 4) {              // pos-emb features c = j8*4 .. +3
            int c = j8 * 4;
            int dpos = s_d[e];
            const float* wp = W_pos + dpos * 16 + c;
            float v[4];
#pragma unroll
            for (int q = 0; q < 4; q++) v[q] = wp[q] + b_pos[c + q];
            float h0 = (float)(_Float16)v[0], h1 = (float)(_Float16)v[1];
            float h2 = (float)(_Float16)v[2], h3 = (float)(_Float16)v[3];
            *(unsigned*)&ah[c + 0] = pack2h(v[0], v[1]);
            *(unsigned*)&ah[c + 2] = pack2h(v[2], v[3]);
            *(unsigned*)&al[c + 0] = pack2h(v[0] - h0, v[1] - h1);
            *(unsigned*)&al[c + 2] = pack2h(v[2] - h2, v[3] - h3);
        }
        // RBF features: c2 = 2*(j8 + 8i), i = 0..24 — covers even 0..398
#pragma unroll 5
        for (int i = 0; i < 25; i++) {
            int c2 = 2 * (j8 + 8 * i);
            int p  = c2 >> 4;
            int r  = c2 & 15;
            float D = dle[p];
            float mu0 = 2.0f + (float)r * (20.0f / 15.0f);
            float mu1 = 2.0f + (float)(r + 1) * (20.0f / 15.0f);
            float t0 = (D - mu0) * 0.8f;
            float t1 = (D - mu1) * 0.8f;
            float g0 = expf(-t0 * t0);
            float g1 = expf(-t1 * t1);
            float h0 = (float)(_Float16)g0, h1 = (float)(_Float16)g1;
            *(unsigned*)&ah[16 + c2] = pack2h(g0, g1);
            *(unsigned*)&al[16 + c2] = pack2h(g0 - h0, g1 - h1);
        }
    }
    __syncthreads();

    // --- MFMA GEMM: 32x416 x 416x128 -> fp32, split precision ---
    int lane  = t & 63;
    int w     = t >> 6;
    int strip = (w & 1) * 16;      // edge strip base
    int h     = w >> 1;            // feature half (0: n 0..63, 1: n 64..127)
    int m     = lane & 15;
    int quad  = lane >> 4;
    const _Float16* pah = &Ah[(strip + m) * ASTRIDE + quad * 8];
    const _Float16* pal = &Al[(strip + m) * ASTRIDE + quad * 8];

    floatx4 acc[4];
#pragma unroll
    for (int c = 0; c < 4; c++) acc[c] = (floatx4){0.f, 0.f, 0.f, 0.f};

    half8 bh[4], bl[4], bnh[4], bnl[4];
#pragma unroll
    for (int c = 0; c < 4; c++) {
        int idx = (h * 4 + c) * 64 + lane;
        bh[c] = Wfh[idx];
        bl[c] = Wfl[idx];
    }

#pragma unroll 1
    for (int kk = 0; kk < KT; kk++) {
        half8 a_hi = *(const half8*)(pah + kk * 32);
        half8 a_lo = *(const half8*)(pal + kk * 32);
        if (kk < KT - 1) {
#pragma unroll
            for (int c = 0; c < 4; c++) {
                int idx = ((kk + 1) * 8 + h * 4 + c) * 64 + lane;
                bnh[c] = Wfh[idx];
                bnl[c] = Wfl[idx];
            }
        }
#pragma unroll
        for (int c = 0; c < 4; c++) {
            acc[c] = __builtin_amdgcn_mfma_f32_16x16x32_f16(a_hi, bh[c], acc[c], 0, 0, 0);
            acc[c] = __builtin_amdgcn_mfma_f32_16x16x32_f16(a_lo, bh[c], acc[c], 0, 0, 0);
            acc[c] = __builtin_amdgcn_mfma_f32_16x16x32_f16(a_hi, bl[c], acc[c], 0, 0, 0);
        }
#pragma unroll
        for (int c = 0; c < 4; c++) { bh[c] = bnh[c]; bl[c] = bnl[c]; }
    }

    // --- LayerNorm epilogue: per edge, features split across wave pairs ---
    // D[row = quad*4 + r][col = m]; edge_local = strip + quad*4 + r.
    int elb = strip + quad * 4;
    float sarr[4];
#pragma unroll
    for (int r = 0; r < 4; r++) {
        float s = acc[0][r] + acc[1][r] + acc[2][r] + acc[3][r];
        for (int msk = 1; msk <= 8; msk <<= 1) s += __shfl_xor(s, msk);
        sarr[r] = s;                       // this wave's 64-feature partial
    }
    if (m == 0) {
#pragma unroll
        for (int r = 0; r < 4; r++) redS[h][elb + r] = sarr[r];
    }
    __syncthreads();
    float mu[4];
#pragma unroll
    for (int r = 0; r < 4; r++) mu[r] = (redS[0][elb + r] + redS[1][elb + r]) * (1.0f / 128.0f);
    __syncthreads();
    float dvv[4][4];
#pragma unroll
    for (int r = 0; r < 4; r++) {
        float v = 0.f;
#pragma unroll
        for (int c = 0; c < 4; c++) { dvv[c][r] = acc[c][r] - mu[r]; v += dvv[c][r] * dvv[c][r]; }
        for (int msk = 1; msk <= 8; msk <<= 1) v += __shfl_xor(v, msk);
        if (m == 0) redS[h][elb + r] = v;
    }
    __syncthreads();
#pragma unroll
    for (int r = 0; r < 4; r++) {
        float var  = (redS[0][elb + r] + redS[1][elb + r]) * (1.0f / 128.0f);
        float rstd = rsqrtf(var + 1e-5f);
        int e = e0 + elb + r;
        float* orow = out + (size_t)e * 128;
#pragma unroll
        for (int c = 0; c < 4; c++) {
            int n = (h * 4 + c) * 16 + m;
            orow[n] = dvv[c][r] * rstd * gamma[n] + beta[n];
        }
    }
}

// ---------------------------------------------------------------------------
extern "C" void kernel_launch(void* const* d_in, const int* in_sizes, int n_in,
                              void* d_out, int out_size, void* d_ws, size_t ws_size,
                              hipStream_t stream) {
    const float* X      = (const float*)d_in[0];
    const float* mask   = (const float*)d_in[1];
    const int*   resi   = (const int*)  d_in[2];
    const float* W_pos  = (const float*)d_in[3];
    const float* b_pos  = (const float*)d_in[4];
    const float* W_edge = (const float*)d_in[5];
    const float* gamma  = (const float*)d_in[6];
    const float* beta   = (const float*)d_in[7];
    float* out = (float*)d_out;

    float* atoms = (float*)d_ws;                                     // 491520 B
    int*   E_idx = (int*)((char*)d_ws + (size_t)NRES * 15 * 4);      // 983040 B
    half8* Wfh   = (half8*)((char*)d_ws + 1474560);                  // 106496 B
    half8* Wfl   = (half8*)((char*)d_ws + 1581056);                  // 106496 B

    atoms_kernel<<<(NRES + 255) / 256, 256, 0, stream>>>(X, atoms);
    wprep_kernel<<<(KT * 8 * 64 + 255) / 256, 256, 0, stream>>>(W_edge, Wfh, Wfl);
    topk_kernel<<<NRES / 4, 256, 0, stream>>>(X, mask, E_idx);
    edge_kernel<<<NEDGE / ME, 256, 0, stream>>>(atoms, E_idx, resi,
                                                W_pos, b_pos, Wfh, Wfl, gamma, beta, out);
}